// Round 1
// baseline (489.673 us; speedup 1.0000x reference)
//
#include <hip/hip_runtime.h>
#include <math.h>

// Problem constants
#define TT 8192      // total tokens (32*16*16)
#define LBATCH 4096  // tokens per mamba batch (b=2)
#define DM 768
#define RR 192
#define DI 384
#define DSTATE 16
#define DTRANK 12

__device__ __forceinline__ float silu_f(float x) { return x / (1.f + __expf(-x)); }
__device__ __forceinline__ float softplus_f(float x) { return x > 20.f ? x : log1pf(__expf(x)); }

// ---------------------------------------------------------------------------
// Generic 64x64 tiled fp32 GEMM: C = A(M,K) @ W(N,K)^T
// MODE 0: plain row-major store (xd)
// MODE 1: transposed split store -> xi_col[b][ch][t] / z_col[b][ch][t]
// MODE 2: out = X + A@W^T  (row-major, residual add)
// ---------------------------------------------------------------------------
template <int MODE>
__global__ __launch_bounds__(256) void gemm_rr(const float* __restrict__ A,
                                               const float* __restrict__ W,
                                               float* __restrict__ C0,
                                               float* __restrict__ C1,
                                               const float* __restrict__ X,
                                               int K, int N)
{
    __shared__ float As[16][68];
    __shared__ float Bs[16][68];
    __shared__ float sC[(MODE == 1) ? 64 * 69 : 1];

    const int tid = threadIdx.x;
    const int ty = tid >> 4, tx = tid & 15;
    const int m0 = blockIdx.y * 64, n0 = blockIdx.x * 64;

    float acc[4][4];
#pragma unroll
    for (int i = 0; i < 4; ++i)
#pragma unroll
        for (int j = 0; j < 4; ++j) acc[i][j] = 0.f;

    const int lm = tid >> 2;          // 0..63 row within tile
    const int lk = (tid & 3) << 2;    // 0,4,8,12
    const float* Ab = A + (size_t)m0 * K;
    const float* Wb = W + (size_t)n0 * K;

    for (int k0 = 0; k0 < K; k0 += 16) {
        const float4 av = *(const float4*)(Ab + (size_t)lm * K + k0 + lk);
        const float4 wv = *(const float4*)(Wb + (size_t)lm * K + k0 + lk);
        __syncthreads();
        As[lk + 0][lm] = av.x; As[lk + 1][lm] = av.y; As[lk + 2][lm] = av.z; As[lk + 3][lm] = av.w;
        Bs[lk + 0][lm] = wv.x; Bs[lk + 1][lm] = wv.y; Bs[lk + 2][lm] = wv.z; Bs[lk + 3][lm] = wv.w;
        __syncthreads();
#pragma unroll
        for (int kk = 0; kk < 16; ++kk) {
            const float4 a4 = *(const float4*)&As[kk][ty << 2];
            const float4 b4 = *(const float4*)&Bs[kk][tx << 2];
            const float aa[4] = {a4.x, a4.y, a4.z, a4.w};
            const float bb[4] = {b4.x, b4.y, b4.z, b4.w};
#pragma unroll
            for (int i = 0; i < 4; ++i)
#pragma unroll
                for (int j = 0; j < 4; ++j)
                    acc[i][j] = fmaf(aa[i], bb[j], acc[i][j]);
        }
    }

    if (MODE == 0) {
#pragma unroll
        for (int i = 0; i < 4; ++i) {
            float4 v = make_float4(acc[i][0], acc[i][1], acc[i][2], acc[i][3]);
            *(float4*)(C0 + (size_t)(m0 + (ty << 2) + i) * N + n0 + (tx << 2)) = v;
        }
    } else if (MODE == 2) {
#pragma unroll
        for (int i = 0; i < 4; ++i) {
            const size_t off = (size_t)(m0 + (ty << 2) + i) * N + n0 + (tx << 2);
            const float4 xv = *(const float4*)(X + off);
            float4 v = make_float4(acc[i][0] + xv.x, acc[i][1] + xv.y,
                                   acc[i][2] + xv.z, acc[i][3] + xv.w);
            *(float4*)(C0 + off) = v;
        }
    } else {
        __syncthreads();
#pragma unroll
        for (int i = 0; i < 4; ++i)
#pragma unroll
            for (int j = 0; j < 4; ++j)
                sC[((ty << 2) + i) * 69 + (tx << 2) + j] = acc[i][j];
        __syncthreads();
        const int b = m0 >> 12, tl0 = m0 & 4095;
        for (int idx = tid; idx < 4096; idx += 256) {
            const int nn = idx >> 6, t = idx & 63;
            const int gch = n0 + nn;
            const float v = sC[t * 69 + nn];
            if (gch < DI)
                C0[((size_t)(b * DI + gch)) * LBATCH + tl0 + t] = v;
            else
                C1[((size_t)(b * DI + gch - DI)) * LBATCH + tl0 + t] = v;
        }
    }
}

// ---------------------------------------------------------------------------
// Depthwise causal conv (width 4) + SiLU.  One block per (b, channel) row.
// ---------------------------------------------------------------------------
__global__ __launch_bounds__(256) void conv_silu_kernel(const float* __restrict__ xi_col,
                                                        const float* __restrict__ cw,
                                                        const float* __restrict__ cb,
                                                        float* __restrict__ u_col)
{
    const int row = blockIdx.x;      // b*384 + c
    const int c = row % DI;
    const float* xp = xi_col + (size_t)row * LBATCH;
    float* up = u_col + (size_t)row * LBATCH;
    const float w0 = cw[c * 4 + 0], w1 = cw[c * 4 + 1], w2 = cw[c * 4 + 2], w3 = cw[c * 4 + 3];
    const float bb = cb[c];
    for (int t = threadIdx.x; t < LBATCH; t += 256) {
        const float x3 = xp[t];
        const float x2 = (t >= 1) ? xp[t - 1] : 0.f;
        const float x1 = (t >= 2) ? xp[t - 2] : 0.f;
        const float x0 = (t >= 3) ? xp[t - 3] : 0.f;
        const float v = bb + w0 * x0 + w1 * x1 + w2 * x2 + w3 * x3;
        up[t] = silu_f(v);
    }
}

// ---------------------------------------------------------------------------
// x_dbl = u @ x_proj^T (N=44, K=384), A read col-major (u_col).
// Outputs: dt row-major (8192x12), BmT/CmT col-major [b][n][t].
// ---------------------------------------------------------------------------
__global__ __launch_bounds__(256) void gemm_xdbl(const float* __restrict__ u_col,
                                                 const float* __restrict__ Wx,
                                                 float* __restrict__ dt,
                                                 float* __restrict__ BmT,
                                                 float* __restrict__ CmT)
{
    __shared__ float As[16][68];
    __shared__ float Bs[16][68];
    __shared__ float sC[64 * 69];
    const int tid = threadIdx.x;
    const int ty = tid >> 4, tx = tid & 15;
    const int m0 = blockIdx.x * 64;
    const int b = m0 >> 12, tl0 = m0 & 4095;

    float acc[4][4];
#pragma unroll
    for (int i = 0; i < 4; ++i)
#pragma unroll
        for (int j = 0; j < 4; ++j) acc[i][j] = 0.f;

    for (int k0 = 0; k0 < DI; k0 += 16) {
        __syncthreads();
        {
            const int m = tid & 63;
            const int kk0 = tid >> 6;
#pragma unroll
            for (int r = 0; r < 4; ++r)
                As[kk0 + 4 * r][m] =
                    u_col[((size_t)(b * DI + k0 + kk0 + 4 * r)) * LBATCH + tl0 + m];
        }
        if (tid < 176) {
            const int n = tid >> 2;
            const int lk2 = (tid & 3) << 2;
            const float4 wv = *(const float4*)(Wx + (size_t)n * DI + k0 + lk2);
            Bs[lk2 + 0][n] = wv.x; Bs[lk2 + 1][n] = wv.y; Bs[lk2 + 2][n] = wv.z; Bs[lk2 + 3][n] = wv.w;
        }
        __syncthreads();
#pragma unroll
        for (int kk = 0; kk < 16; ++kk) {
            const float4 a4 = *(const float4*)&As[kk][ty << 2];
            const float4 b4 = *(const float4*)&Bs[kk][tx << 2];
            const float aa[4] = {a4.x, a4.y, a4.z, a4.w};
            const float bb[4] = {b4.x, b4.y, b4.z, b4.w};
#pragma unroll
            for (int i = 0; i < 4; ++i)
#pragma unroll
                for (int j = 0; j < 4; ++j)
                    acc[i][j] = fmaf(aa[i], bb[j], acc[i][j]);
        }
    }
    __syncthreads();
#pragma unroll
    for (int i = 0; i < 4; ++i)
#pragma unroll
        for (int j = 0; j < 4; ++j)
            sC[((ty << 2) + i) * 69 + (tx << 2) + j] = acc[i][j];
    __syncthreads();
    for (int idx = tid; idx < 64 * DTRANK; idx += 256) {
        const int t = idx / DTRANK, r = idx - t * DTRANK;
        dt[(size_t)(m0 + t) * DTRANK + r] = sC[t * 69 + r];
    }
    for (int idx = tid; idx < 64 * DSTATE; idx += 256) {
        const int n = idx >> 6, t = idx & 63;
        BmT[((size_t)(b * DSTATE + n)) * LBATCH + tl0 + t] = sC[t * 69 + DTRANK + n];
        CmT[((size_t)(b * DSTATE + n)) * LBATCH + tl0 + t] = sC[t * 69 + DTRANK + DSTATE + n];
    }
}

// ---------------------------------------------------------------------------
// delta = softplus(dt @ dt_proj^T + dt_proj_b), written col-major [b][d][t]
// ---------------------------------------------------------------------------
__global__ __launch_bounds__(256) void delta_kernel(const float* __restrict__ dt,
                                                    const float* __restrict__ dtw,
                                                    const float* __restrict__ dtb,
                                                    float* __restrict__ delta_col)
{
    const int t0g = blockIdx.x * 64;
    const int d0 = blockIdx.y * 64;
    const int b = t0g >> 12, tl0 = t0g & 4095;
    __shared__ float sdt[64][13];
    const int tid = threadIdx.x;
    for (int idx = tid; idx < 64 * DTRANK; idx += 256)
        sdt[idx / DTRANK][idx % DTRANK] = dt[(size_t)t0g * DTRANK + idx];
    __syncthreads();
    const int tl = tid & 63;
    const int dl0 = tid >> 6;  // wave id 0..3
#pragma unroll
    for (int j = 0; j < 16; ++j) {
        const int d = d0 + dl0 + 4 * j;
        float a = dtb[d];
#pragma unroll
        for (int r = 0; r < DTRANK; ++r)
            a = fmaf(sdt[tl][r], dtw[d * DTRANK + r], a);
        delta_col[((size_t)(b * DI + d)) * LBATCH + tl0 + tl] = softplus_f(a);
    }
}

// ---------------------------------------------------------------------------
// Selective scan. One block per (b, d); 16 waves = 16 states n; lane = t
// within a 64-step chunk; 64 sequential chunks. Wave-parallel affine scan.
// Fuses y = (ys + u*D) * silu(z) -> y_col[b][d][t].
// ---------------------------------------------------------------------------
__global__ __launch_bounds__(1024) void scan_kernel(const float* __restrict__ delta_col,
                                                    const float* __restrict__ u_col,
                                                    const float* __restrict__ BmT,
                                                    const float* __restrict__ CmT,
                                                    const float* __restrict__ z_col,
                                                    const float* __restrict__ A_log,
                                                    const float* __restrict__ Dv,
                                                    float* __restrict__ y_col)
{
    const int bd = blockIdx.x;       // 0..767
    const int b = bd / DI;
    const int d = bd - b * DI;
    const int tid = threadIdx.x;
    const int n = tid >> 6;          // state index (wave id)
    const int lane = tid & 63;

    const float Aval = -__expf(A_log[d * DSTATE + n]);
    const float Dd = Dv[d];
    const float* dp = delta_col + ((size_t)(b * DI + d)) * LBATCH;
    const float* up = u_col + ((size_t)(b * DI + d)) * LBATCH;
    const float* zp = z_col + ((size_t)(b * DI + d)) * LBATCH;
    const float* bp = BmT + ((size_t)(b * DSTATE + n)) * LBATCH;
    const float* cp = CmT + ((size_t)(b * DSTATE + n)) * LBATCH;
    float* yp = y_col + ((size_t)(b * DI + d)) * LBATCH;

    __shared__ float p_lds[16][64];
    float h0 = 0.f;

    for (int c = 0; c < 64; ++c) {
        const int t = c * 64 + lane;
        const float dl = dp[t];
        const float uu = up[t];
        const float bm = bp[t];
        float a = __expf(dl * Aval);
        float bb = dl * uu * bm;
        // inclusive Hillis-Steele scan of affine transforms over 64 lanes
#pragma unroll
        for (int o = 1; o < 64; o <<= 1) {
            const float ua = __shfl_up(a, (unsigned)o, 64);
            const float ub = __shfl_up(bb, (unsigned)o, 64);
            if (lane >= o) {
                bb = fmaf(a, ub, bb);
                a *= ua;
            }
        }
        const float h = fmaf(a, h0, bb);
        h0 = __shfl(h, 63, 64);
        p_lds[n][lane] = h * cp[t];
        __syncthreads();
        if (tid < 64) {
            float s = 0.f;
#pragma unroll
            for (int q = 0; q < 16; ++q) s += p_lds[q][tid];
            const float zz = zp[c * 64 + tid];
            const float y = (s + uu * Dd) * silu_f(zz);  // tid<64 => lane==tid, uu valid
            yp[c * 64 + tid] = y;
        }
        __syncthreads();
    }
}

// ---------------------------------------------------------------------------
// m = y @ out_proj^T (K=384, N=192 full row per block) + LayerNorm + exact GELU.
// A read col-major (y_col). BM=32 rows per block.
// ---------------------------------------------------------------------------
__global__ __launch_bounds__(256) void gemm_ln(const float* __restrict__ ycol,
                                               const float* __restrict__ Wo,
                                               const float* __restrict__ lng,
                                               const float* __restrict__ lnb,
                                               float* __restrict__ G)
{
    __shared__ float As[16][36];
    __shared__ float Bs[16][200];
    const int tid = threadIdx.x;
    const int ty = tid >> 4, tx = tid & 15;
    const int m0 = blockIdx.x * 32;
    const int b = m0 >> 12, tl0 = m0 & 4095;

    float acc[2][12];
#pragma unroll
    for (int i = 0; i < 2; ++i)
#pragma unroll
        for (int j = 0; j < 12; ++j) acc[i][j] = 0.f;

    for (int k0 = 0; k0 < DI; k0 += 16) {
        __syncthreads();
        {
            const int m = tid & 31;
            const int kk = tid >> 5;  // 0..7
            As[kk][m] = ycol[((size_t)(b * DI + k0 + kk)) * LBATCH + tl0 + m];
            As[kk + 8][m] = ycol[((size_t)(b * DI + k0 + kk + 8)) * LBATCH + tl0 + m];
        }
        for (int idx = tid; idx < 768; idx += 256) {
            const int nn = idx >> 2;
            const int lk2 = (idx & 3) << 2;
            const float4 wv = *(const float4*)(Wo + (size_t)nn * DI + k0 + lk2);
            Bs[lk2 + 0][nn] = wv.x; Bs[lk2 + 1][nn] = wv.y; Bs[lk2 + 2][nn] = wv.z; Bs[lk2 + 3][nn] = wv.w;
        }
        __syncthreads();
#pragma unroll
        for (int kk = 0; kk < 16; ++kk) {
            const float a0 = As[kk][ty * 2 + 0];
            const float a1 = As[kk][ty * 2 + 1];
            const float4 b0 = *(const float4*)&Bs[kk][tx * 12 + 0];
            const float4 b1 = *(const float4*)&Bs[kk][tx * 12 + 4];
            const float4 b2 = *(const float4*)&Bs[kk][tx * 12 + 8];
            const float bv[12] = {b0.x, b0.y, b0.z, b0.w, b1.x, b1.y, b1.z, b1.w, b2.x, b2.y, b2.z, b2.w};
#pragma unroll
            for (int j = 0; j < 12; ++j) {
                acc[0][j] = fmaf(a0, bv[j], acc[0][j]);
                acc[1][j] = fmaf(a1, bv[j], acc[1][j]);
            }
        }
    }

    // LayerNorm over 192 columns per row
    __shared__ float rsum[32][17];
    __shared__ float rsq[32][17];
    __shared__ float smu[32];
    __shared__ float srs[32];
#pragma unroll
    for (int i = 0; i < 2; ++i) {
        float s = 0.f, q = 0.f;
#pragma unroll
        for (int j = 0; j < 12; ++j) {
            s += acc[i][j];
            q = fmaf(acc[i][j], acc[i][j], q);
        }
        rsum[ty * 2 + i][tx] = s;
        rsq[ty * 2 + i][tx] = q;
    }
    __syncthreads();
    if (tid < 32) {
        float s = 0.f, q = 0.f;
#pragma unroll
        for (int xk = 0; xk < 16; ++xk) {
            s += rsum[tid][xk];
            q += rsq[tid][xk];
        }
        const float mu = s * (1.f / 192.f);
        const float var = q * (1.f / 192.f) - mu * mu;
        smu[tid] = mu;
        srs[tid] = rsqrtf(var + 1e-5f);
    }
    __syncthreads();
#pragma unroll
    for (int i = 0; i < 2; ++i) {
        const int m = m0 + ty * 2 + i;
        const float mu = smu[ty * 2 + i];
        const float rs = srs[ty * 2 + i];
        float tmp[12];
#pragma unroll
        for (int j = 0; j < 12; ++j) {
            const int nn = tx * 12 + j;
            float v = (acc[i][j] - mu) * rs * lng[nn] + lnb[nn];
            tmp[j] = 0.5f * v * (1.f + erff(v * 0.70710678118654752f));
        }
        float* gp = G + (size_t)m * RR + tx * 12;
        *(float4*)(gp + 0) = make_float4(tmp[0], tmp[1], tmp[2], tmp[3]);
        *(float4*)(gp + 4) = make_float4(tmp[4], tmp[5], tmp[6], tmp[7]);
        *(float4*)(gp + 8) = make_float4(tmp[8], tmp[9], tmp[10], tmp[11]);
    }
}

// ---------------------------------------------------------------------------
extern "C" void kernel_launch(void* const* d_in, const int* in_sizes, int n_in,
                              void* d_out, int out_size, void* d_ws, size_t ws_size,
                              hipStream_t stream)
{
    const float* x         = (const float*)d_in[0];
    const float* down_w    = (const float*)d_in[1];
    const float* up_w      = (const float*)d_in[2];
    const float* in_proj_w = (const float*)d_in[3];
    const float* conv_w    = (const float*)d_in[4];
    const float* conv_b    = (const float*)d_in[5];
    const float* x_proj_w  = (const float*)d_in[6];
    const float* dt_proj_w = (const float*)d_in[7];
    const float* dt_proj_b = (const float*)d_in[8];
    const float* A_log     = (const float*)d_in[9];
    const float* D_ssm     = (const float*)d_in[10];
    const float* out_proj_w= (const float*)d_in[11];
    const float* ln_g      = (const float*)d_in[12];
    const float* ln_b      = (const float*)d_in[13];
    float* out = (float*)d_out;
    float* ws = (float*)d_ws;

    // workspace layout (floats)
    float* xd        = ws;                        // 8192*192   = 1572864
    float* xi_col    = xd + 1572864;              // 2*384*4096 = 3145728
    float* z_col     = xi_col + 3145728;          // 3145728
    float* u_col     = z_col + 3145728;           // 3145728
    float* dt        = u_col + 3145728;           // 8192*12    = 98304
    float* BmT       = dt + 98304;                // 2*16*4096  = 131072
    float* CmT       = BmT + 131072;              // 131072
    float* delta_col = CmT + 131072;              // 3145728
    float* y_col     = delta_col + 3145728;       // 3145728
    float* g         = xd;                        // alias: xd dead after in_proj

    // 1. xd = x @ down_w^T                     (8192x768 @ 768x192)
    gemm_rr<0><<<dim3(3, 128), 256, 0, stream>>>(x, down_w, xd, nullptr, nullptr, DM, RR);
    // 2. xz = xd @ in_proj^T -> xi_col, z_col  (8192x192 @ 192x768)
    gemm_rr<1><<<dim3(12, 128), 256, 0, stream>>>(xd, in_proj_w, xi_col, z_col, nullptr, RR, 2 * DI);
    // 3. depthwise conv4 + silu -> u_col
    conv_silu_kernel<<<768, 256, 0, stream>>>(xi_col, conv_w, conv_b, u_col);
    // 4. x_dbl = u @ x_proj^T -> dt, BmT, CmT
    gemm_xdbl<<<128, 256, 0, stream>>>(u_col, x_proj_w, dt, BmT, CmT);
    // 5. delta = softplus(dt @ dt_proj^T + b) -> delta_col
    delta_kernel<<<dim3(128, 6), 256, 0, stream>>>(dt, dt_proj_w, dt_proj_b, delta_col);
    // 6. selective scan + gating -> y_col
    scan_kernel<<<768, 1024, 0, stream>>>(delta_col, u_col, BmT, CmT, z_col, A_log, D_ssm, y_col);
    // 7. m = y @ out_proj^T, LN, gelu -> g
    gemm_ln<<<256, 256, 0, stream>>>(y_col, out_proj_w, ln_g, ln_b, g);
    // 8. out = x + g @ up_w^T
    gemm_rr<2><<<dim3(12, 128), 256, 0, stream>>>(g, up_w, out, nullptr, x, RR, DM);
}

// Round 2
// 393.597 us; speedup vs baseline: 1.2441x; 1.2441x over previous
//
#include <hip/hip_runtime.h>
#include <math.h>

// Problem constants
#define TT 8192      // total tokens (32*16*16)
#define LBATCH 4096  // tokens per mamba batch (b=2)
#define DM 768
#define RR 192
#define DI 384
#define DSTATE 16
#define DTRANK 12

__device__ __forceinline__ float silu_f(float x) { return x / (1.f + __expf(-x)); }
__device__ __forceinline__ float softplus_f(float x) { return x > 20.f ? x : log1pf(__expf(x)); }

// DPP-based partial sum across each aligned 16-lane group (VALU pipe, no LDS).
template <int CTRL>
__device__ __forceinline__ float dpp_add(float x) {
    const int y = __builtin_amdgcn_update_dpp(0, __float_as_int(x), CTRL, 0xF, 0xF, false);
    return x + __int_as_float(y);
}

// ---------------------------------------------------------------------------
// Generic 64x64 tiled fp32 GEMM: C = A(M,K) @ W(N,K)^T
// MODE 0: plain row-major store (xd)
// MODE 1: transposed split store -> xi_col[b][ch][t] / z_col[b][ch][t]
// MODE 2: out = X + A@W^T  (row-major, residual add)
// ---------------------------------------------------------------------------
template <int MODE>
__global__ __launch_bounds__(256) void gemm_rr(const float* __restrict__ A,
                                               const float* __restrict__ W,
                                               float* __restrict__ C0,
                                               float* __restrict__ C1,
                                               const float* __restrict__ X,
                                               int K, int N)
{
    __shared__ float As[16][68];
    __shared__ float Bs[16][68];
    __shared__ float sC[(MODE == 1) ? 64 * 69 : 1];

    const int tid = threadIdx.x;
    const int ty = tid >> 4, tx = tid & 15;
    const int m0 = blockIdx.y * 64, n0 = blockIdx.x * 64;

    float acc[4][4];
#pragma unroll
    for (int i = 0; i < 4; ++i)
#pragma unroll
        for (int j = 0; j < 4; ++j) acc[i][j] = 0.f;

    const int lm = tid >> 2;          // 0..63 row within tile
    const int lk = (tid & 3) << 2;    // 0,4,8,12
    const float* Ab = A + (size_t)m0 * K;
    const float* Wb = W + (size_t)n0 * K;

    for (int k0 = 0; k0 < K; k0 += 16) {
        const float4 av = *(const float4*)(Ab + (size_t)lm * K + k0 + lk);
        const float4 wv = *(const float4*)(Wb + (size_t)lm * K + k0 + lk);
        __syncthreads();
        As[lk + 0][lm] = av.x; As[lk + 1][lm] = av.y; As[lk + 2][lm] = av.z; As[lk + 3][lm] = av.w;
        Bs[lk + 0][lm] = wv.x; Bs[lk + 1][lm] = wv.y; Bs[lk + 2][lm] = wv.z; Bs[lk + 3][lm] = wv.w;
        __syncthreads();
#pragma unroll
        for (int kk = 0; kk < 16; ++kk) {
            const float4 a4 = *(const float4*)&As[kk][ty << 2];
            const float4 b4 = *(const float4*)&Bs[kk][tx << 2];
            const float aa[4] = {a4.x, a4.y, a4.z, a4.w};
            const float bb[4] = {b4.x, b4.y, b4.z, b4.w};
#pragma unroll
            for (int i = 0; i < 4; ++i)
#pragma unroll
                for (int j = 0; j < 4; ++j)
                    acc[i][j] = fmaf(aa[i], bb[j], acc[i][j]);
        }
    }

    if (MODE == 0) {
#pragma unroll
        for (int i = 0; i < 4; ++i) {
            float4 v = make_float4(acc[i][0], acc[i][1], acc[i][2], acc[i][3]);
            *(float4*)(C0 + (size_t)(m0 + (ty << 2) + i) * N + n0 + (tx << 2)) = v;
        }
    } else if (MODE == 2) {
#pragma unroll
        for (int i = 0; i < 4; ++i) {
            const size_t off = (size_t)(m0 + (ty << 2) + i) * N + n0 + (tx << 2);
            const float4 xv = *(const float4*)(X + off);
            float4 v = make_float4(acc[i][0] + xv.x, acc[i][1] + xv.y,
                                   acc[i][2] + xv.z, acc[i][3] + xv.w);
            *(float4*)(C0 + off) = v;
        }
    } else {
        __syncthreads();
#pragma unroll
        for (int i = 0; i < 4; ++i)
#pragma unroll
            for (int j = 0; j < 4; ++j)
                sC[((ty << 2) + i) * 69 + (tx << 2) + j] = acc[i][j];
        __syncthreads();
        const int b = m0 >> 12, tl0 = m0 & 4095;
        for (int idx = tid; idx < 4096; idx += 256) {
            const int nn = idx >> 6, t = idx & 63;
            const int gch = n0 + nn;
            const float v = sC[t * 69 + nn];
            if (gch < DI)
                C0[((size_t)(b * DI + gch)) * LBATCH + tl0 + t] = v;
            else
                C1[((size_t)(b * DI + gch - DI)) * LBATCH + tl0 + t] = v;
        }
    }
}

// ---------------------------------------------------------------------------
// Depthwise causal conv (width 4) + SiLU.  One block per (b, channel) row.
// ---------------------------------------------------------------------------
__global__ __launch_bounds__(256) void conv_silu_kernel(const float* __restrict__ xi_col,
                                                        const float* __restrict__ cw,
                                                        const float* __restrict__ cb,
                                                        float* __restrict__ u_col)
{
    const int row = blockIdx.x;      // b*384 + c
    const int c = row % DI;
    const float* xp = xi_col + (size_t)row * LBATCH;
    float* up = u_col + (size_t)row * LBATCH;
    const float w0 = cw[c * 4 + 0], w1 = cw[c * 4 + 1], w2 = cw[c * 4 + 2], w3 = cw[c * 4 + 3];
    const float bb = cb[c];
    for (int t = threadIdx.x; t < LBATCH; t += 256) {
        const float x3 = xp[t];
        const float x2 = (t >= 1) ? xp[t - 1] : 0.f;
        const float x1 = (t >= 2) ? xp[t - 2] : 0.f;
        const float x0 = (t >= 3) ? xp[t - 3] : 0.f;
        const float v = bb + w0 * x0 + w1 * x1 + w2 * x2 + w3 * x3;
        up[t] = silu_f(v);
    }
}

// ---------------------------------------------------------------------------
// x_dbl = u @ x_proj^T (N=44, K=384), A read col-major (u_col).
// Outputs: dt row-major (8192x12), BCt interleaved [b][t][32] (B 0..15, C 16..31).
// ---------------------------------------------------------------------------
__global__ __launch_bounds__(256) void gemm_xdbl(const float* __restrict__ u_col,
                                                 const float* __restrict__ Wx,
                                                 float* __restrict__ dt,
                                                 float* __restrict__ BCt)
{
    __shared__ float As[16][68];
    __shared__ float Bs[16][68];
    __shared__ float sC[64 * 69];
    const int tid = threadIdx.x;
    const int ty = tid >> 4, tx = tid & 15;
    const int m0 = blockIdx.x * 64;
    const int b = m0 >> 12, tl0 = m0 & 4095;

    float acc[4][4];
#pragma unroll
    for (int i = 0; i < 4; ++i)
#pragma unroll
        for (int j = 0; j < 4; ++j) acc[i][j] = 0.f;

    for (int k0 = 0; k0 < DI; k0 += 16) {
        __syncthreads();
        {
            const int m = tid & 63;
            const int kk0 = tid >> 6;
#pragma unroll
            for (int r = 0; r < 4; ++r)
                As[kk0 + 4 * r][m] =
                    u_col[((size_t)(b * DI + k0 + kk0 + 4 * r)) * LBATCH + tl0 + m];
        }
        if (tid < 176) {
            const int n = tid >> 2;
            const int lk2 = (tid & 3) << 2;
            const float4 wv = *(const float4*)(Wx + (size_t)n * DI + k0 + lk2);
            Bs[lk2 + 0][n] = wv.x; Bs[lk2 + 1][n] = wv.y; Bs[lk2 + 2][n] = wv.z; Bs[lk2 + 3][n] = wv.w;
        }
        __syncthreads();
#pragma unroll
        for (int kk = 0; kk < 16; ++kk) {
            const float4 a4 = *(const float4*)&As[kk][ty << 2];
            const float4 b4 = *(const float4*)&Bs[kk][tx << 2];
            const float aa[4] = {a4.x, a4.y, a4.z, a4.w};
            const float bb[4] = {b4.x, b4.y, b4.z, b4.w};
#pragma unroll
            for (int i = 0; i < 4; ++i)
#pragma unroll
                for (int j = 0; j < 4; ++j)
                    acc[i][j] = fmaf(aa[i], bb[j], acc[i][j]);
        }
    }
    __syncthreads();
#pragma unroll
    for (int i = 0; i < 4; ++i)
#pragma unroll
        for (int j = 0; j < 4; ++j)
            sC[((ty << 2) + i) * 69 + (tx << 2) + j] = acc[i][j];
    __syncthreads();
    for (int idx = tid; idx < 64 * DTRANK; idx += 256) {
        const int t = idx / DTRANK, r = idx - t * DTRANK;
        dt[(size_t)(m0 + t) * DTRANK + r] = sC[t * 69 + r];
    }
    for (int idx = tid; idx < 64 * 32; idx += 256) {
        const int t = idx >> 5, c = idx & 31;
        BCt[((size_t)(b * LBATCH + tl0 + t)) * 32 + c] = sC[t * 69 + DTRANK + c];
    }
}

// ---------------------------------------------------------------------------
// delta = softplus(dt @ dt_proj^T + dt_proj_b), written col-major [b][d][t]
// ---------------------------------------------------------------------------
__global__ __launch_bounds__(256) void delta_kernel(const float* __restrict__ dt,
                                                    const float* __restrict__ dtw,
                                                    const float* __restrict__ dtb,
                                                    float* __restrict__ delta_col)
{
    const int t0g = blockIdx.x * 64;
    const int d0 = blockIdx.y * 64;
    const int b = t0g >> 12, tl0 = t0g & 4095;
    __shared__ float sdt[64][13];
    const int tid = threadIdx.x;
    for (int idx = tid; idx < 64 * DTRANK; idx += 256)
        sdt[idx / DTRANK][idx % DTRANK] = dt[(size_t)t0g * DTRANK + idx];
    __syncthreads();
    const int tl = tid & 63;
    const int dl0 = tid >> 6;  // wave id 0..3
#pragma unroll
    for (int j = 0; j < 16; ++j) {
        const int d = d0 + dl0 + 4 * j;
        float a = dtb[d];
#pragma unroll
        for (int r = 0; r < DTRANK; ++r)
            a = fmaf(sdt[tl][r], dtw[d * DTRANK + r], a);
        delta_col[((size_t)(b * DI + d)) * LBATCH + tl0 + tl] = softplus_f(a);
    }
}

// ---------------------------------------------------------------------------
// Selective scan v2: two-level segmented scan, 2 barriers total.
// Block = (b, d). Thread (n = tid&15, s = tid>>4): state n, 64-step segment s.
// Phase 1: serial affine aggregate per segment (no cross-thread comms).
// Wave scan (wave = state n, lane = segment) -> per-segment initial state.
// Phase 2: serial replay; 16-state sum per timestep via DPP (VALU only).
// ---------------------------------------------------------------------------
__global__ __launch_bounds__(1024) void scan_kernel(const float* __restrict__ delta_col,
                                                    const float* __restrict__ u_col,
                                                    const float* __restrict__ BCt,
                                                    const float* __restrict__ z_col,
                                                    const float* __restrict__ A_log,
                                                    const float* __restrict__ Dv,
                                                    float* __restrict__ y_col)
{
    const int bd = blockIdx.x;       // b*384 + d
    const int b = bd / DI;
    const int d = bd - b * DI;
    const int tid = threadIdx.x;
    const int n = tid & 15;          // state index
    const int s = tid >> 4;          // segment index 0..63

    const float An = -__expf(A_log[d * DSTATE + n]);
    const float Dd = Dv[d];
    const float* dp = delta_col + (size_t)bd * LBATCH;
    const float* up = u_col + (size_t)bd * LBATCH;
    const float* zp = z_col + (size_t)bd * LBATCH;
    const float* bc = BCt + (size_t)b * LBATCH * 32;
    float* yp = y_col + (size_t)bd * LBATCH;

    __shared__ float aggA[64][17];
    __shared__ float aggB[64][17];
    __shared__ float hst[64][17];

    const int t0 = s * 64;

    // ---- phase 1: segment aggregate (A,Bg): h_out = A*h_in + Bg ----
    float Ag = 1.f, Bg = 0.f;
    for (int i = 0; i < 64; i += 4) {
        const float4 d4 = *(const float4*)(dp + t0 + i);
        const float4 u4 = *(const float4*)(up + t0 + i);
        const float dls[4] = {d4.x, d4.y, d4.z, d4.w};
        const float uus[4] = {u4.x, u4.y, u4.z, u4.w};
#pragma unroll
        for (int j = 0; j < 4; ++j) {
            const int t = t0 + i + j;
            const float bm = bc[(size_t)t * 32 + n];
            const float a = __expf(dls[j] * An);
            const float bb = dls[j] * uus[j] * bm;
            Bg = fmaf(a, Bg, bb);
            Ag *= a;
        }
    }
    aggA[s][n] = Ag;
    aggB[s][n] = Bg;
    __syncthreads();

    // ---- wave-level inclusive affine scan over 64 segments (wave = state) ----
    {
        const int w = tid >> 6;      // 0..15 = state handled by this wave
        const int lane = tid & 63;   // segment
        float sA = aggA[lane][w];
        float sB = aggB[lane][w];
#pragma unroll
        for (int o = 1; o < 64; o <<= 1) {
            const float pA = __shfl_up(sA, (unsigned)o, 64);
            const float pB = __shfl_up(sB, (unsigned)o, 64);
            if (lane >= o) { sB = fmaf(sA, pB, sB); sA *= pA; }
        }
        const float hprev = __shfl_up(sB, 1, 64);
        hst[lane][w] = (lane == 0) ? 0.f : hprev;   // state entering segment
    }
    __syncthreads();

    // ---- phase 2: replay segment with correct h0, reduce over n via DPP ----
    float h = hst[s][n];
    for (int i = 0; i < 64; i += 4) {
        const float4 d4 = *(const float4*)(dp + t0 + i);
        const float4 u4 = *(const float4*)(up + t0 + i);
        const float4 z4 = *(const float4*)(zp + t0 + i);
        const float dls[4] = {d4.x, d4.y, d4.z, d4.w};
        const float uus[4] = {u4.x, u4.y, u4.z, u4.w};
        const float zzs[4] = {z4.x, z4.y, z4.z, z4.w};
#pragma unroll
        for (int j = 0; j < 4; ++j) {
            const int t = t0 + i + j;
            const float bm = bc[(size_t)t * 32 + n];
            const float cm = bc[(size_t)t * 32 + 16 + n];
            const float a = __expf(dls[j] * An);
            h = fmaf(a, h, dls[j] * uus[j] * bm);
            float p = h * cm;
            // sum across the 16 states (aligned 16-lane group), VALU-only
            p = dpp_add<0xB1>(p);    // quad_perm xor1
            p = dpp_add<0x4E>(p);    // quad_perm xor2
            p = dpp_add<0x124>(p);   // row_ror:4
            p = dpp_add<0x128>(p);   // row_ror:8
            if (n == 0)
                yp[t] = (p + uus[j] * Dd) * silu_f(zzs[j]);
        }
    }
}

// ---------------------------------------------------------------------------
// m = y @ out_proj^T (K=384, N=192 full row per block) + LayerNorm + exact GELU.
// A read col-major (y_col). BM=32 rows per block.
// ---------------------------------------------------------------------------
__global__ __launch_bounds__(256) void gemm_ln(const float* __restrict__ ycol,
                                               const float* __restrict__ Wo,
                                               const float* __restrict__ lng,
                                               const float* __restrict__ lnb,
                                               float* __restrict__ G)
{
    __shared__ float As[16][36];
    __shared__ float Bs[16][200];
    const int tid = threadIdx.x;
    const int ty = tid >> 4, tx = tid & 15;
    const int m0 = blockIdx.x * 32;
    const int b = m0 >> 12, tl0 = m0 & 4095;

    float acc[2][12];
#pragma unroll
    for (int i = 0; i < 2; ++i)
#pragma unroll
        for (int j = 0; j < 12; ++j) acc[i][j] = 0.f;

    for (int k0 = 0; k0 < DI; k0 += 16) {
        __syncthreads();
        {
            const int m = tid & 31;
            const int kk = tid >> 5;  // 0..7
            As[kk][m] = ycol[((size_t)(b * DI + k0 + kk)) * LBATCH + tl0 + m];
            As[kk + 8][m] = ycol[((size_t)(b * DI + k0 + kk + 8)) * LBATCH + tl0 + m];
        }
        for (int idx = tid; idx < 768; idx += 256) {
            const int nn = idx >> 2;
            const int lk2 = (idx & 3) << 2;
            const float4 wv = *(const float4*)(Wo + (size_t)nn * DI + k0 + lk2);
            Bs[lk2 + 0][nn] = wv.x; Bs[lk2 + 1][nn] = wv.y; Bs[lk2 + 2][nn] = wv.z; Bs[lk2 + 3][nn] = wv.w;
        }
        __syncthreads();
#pragma unroll
        for (int kk = 0; kk < 16; ++kk) {
            const float a0 = As[kk][ty * 2 + 0];
            const float a1 = As[kk][ty * 2 + 1];
            const float4 b0 = *(const float4*)&Bs[kk][tx * 12 + 0];
            const float4 b1 = *(const float4*)&Bs[kk][tx * 12 + 4];
            const float4 b2 = *(const float4*)&Bs[kk][tx * 12 + 8];
            const float bv[12] = {b0.x, b0.y, b0.z, b0.w, b1.x, b1.y, b1.z, b1.w, b2.x, b2.y, b2.z, b2.w};
#pragma unroll
            for (int j = 0; j < 12; ++j) {
                acc[0][j] = fmaf(a0, bv[j], acc[0][j]);
                acc[1][j] = fmaf(a1, bv[j], acc[1][j]);
            }
        }
    }

    // LayerNorm over 192 columns per row
    __shared__ float rsum[32][17];
    __shared__ float rsq[32][17];
    __shared__ float smu[32];
    __shared__ float srs[32];
#pragma unroll
    for (int i = 0; i < 2; ++i) {
        float s = 0.f, q = 0.f;
#pragma unroll
        for (int j = 0; j < 12; ++j) {
            s += acc[i][j];
            q = fmaf(acc[i][j], acc[i][j], q);
        }
        rsum[ty * 2 + i][tx] = s;
        rsq[ty * 2 + i][tx] = q;
    }
    __syncthreads();
    if (tid < 32) {
        float s = 0.f, q = 0.f;
#pragma unroll
        for (int xk = 0; xk < 16; ++xk) {
            s += rsum[tid][xk];
            q += rsq[tid][xk];
        }
        const float mu = s * (1.f / 192.f);
        const float var = q * (1.f / 192.f) - mu * mu;
        smu[tid] = mu;
        srs[tid] = rsqrtf(var + 1e-5f);
    }
    __syncthreads();
#pragma unroll
    for (int i = 0; i < 2; ++i) {
        const int m = m0 + ty * 2 + i;
        const float mu = smu[ty * 2 + i];
        const float rs = srs[ty * 2 + i];
        float tmp[12];
#pragma unroll
        for (int j = 0; j < 12; ++j) {
            const int nn = tx * 12 + j;
            float v = (acc[i][j] - mu) * rs * lng[nn] + lnb[nn];
            tmp[j] = 0.5f * v * (1.f + erff(v * 0.70710678118654752f));
        }
        float* gp = G + (size_t)m * RR + tx * 12;
        *(float4*)(gp + 0) = make_float4(tmp[0], tmp[1], tmp[2], tmp[3]);
        *(float4*)(gp + 4) = make_float4(tmp[4], tmp[5], tmp[6], tmp[7]);
        *(float4*)(gp + 8) = make_float4(tmp[8], tmp[9], tmp[10], tmp[11]);
    }
}

// ---------------------------------------------------------------------------
extern "C" void kernel_launch(void* const* d_in, const int* in_sizes, int n_in,
                              void* d_out, int out_size, void* d_ws, size_t ws_size,
                              hipStream_t stream)
{
    const float* x         = (const float*)d_in[0];
    const float* down_w    = (const float*)d_in[1];
    const float* up_w      = (const float*)d_in[2];
    const float* in_proj_w = (const float*)d_in[3];
    const float* conv_w    = (const float*)d_in[4];
    const float* conv_b    = (const float*)d_in[5];
    const float* x_proj_w  = (const float*)d_in[6];
    const float* dt_proj_w = (const float*)d_in[7];
    const float* dt_proj_b = (const float*)d_in[8];
    const float* A_log     = (const float*)d_in[9];
    const float* D_ssm     = (const float*)d_in[10];
    const float* out_proj_w= (const float*)d_in[11];
    const float* ln_g      = (const float*)d_in[12];
    const float* ln_b      = (const float*)d_in[13];
    float* out = (float*)d_out;
    float* ws = (float*)d_ws;

    // workspace layout (floats)
    float* xd        = ws;                        // 8192*192   = 1572864
    float* xi_col    = xd + 1572864;              // 2*384*4096 = 3145728
    float* z_col     = xi_col + 3145728;          // 3145728
    float* u_col     = z_col + 3145728;           // 3145728
    float* dt        = u_col + 3145728;           // 8192*12    = 98304
    float* BCt       = dt + 98304;                // 2*4096*32  = 262144
    float* delta_col = BCt + 262144;              // 3145728
    float* y_col     = delta_col + 3145728;       // 3145728
    float* g         = xd;                        // alias: xd dead after in_proj

    // 1. xd = x @ down_w^T                     (8192x768 @ 768x192)
    gemm_rr<0><<<dim3(3, 128), 256, 0, stream>>>(x, down_w, xd, nullptr, nullptr, DM, RR);
    // 2. xz = xd @ in_proj^T -> xi_col, z_col  (8192x192 @ 192x768)
    gemm_rr<1><<<dim3(12, 128), 256, 0, stream>>>(xd, in_proj_w, xi_col, z_col, nullptr, RR, 2 * DI);
    // 3. depthwise conv4 + silu -> u_col
    conv_silu_kernel<<<768, 256, 0, stream>>>(xi_col, conv_w, conv_b, u_col);
    // 4. x_dbl = u @ x_proj^T -> dt, BCt
    gemm_xdbl<<<128, 256, 0, stream>>>(u_col, x_proj_w, dt, BCt);
    // 5. delta = softplus(dt @ dt_proj^T + b) -> delta_col
    delta_kernel<<<dim3(128, 6), 256, 0, stream>>>(dt, dt_proj_w, dt_proj_b, delta_col);
    // 6. selective scan v2 + gating -> y_col
    scan_kernel<<<768, 1024, 0, stream>>>(delta_col, u_col, BCt, z_col, A_log, D_ssm, y_col);
    // 7. m = y @ out_proj^T, LN, gelu -> g
    gemm_ln<<<256, 256, 0, stream>>>(y_col, out_proj_w, ln_g, ln_b, g);
    // 8. out = x + g @ up_w^T
    gemm_rr<2><<<dim3(12, 128), 256, 0, stream>>>(g, up_w, out, nullptr, x, RR, DM);
}

// Round 3
// 299.422 us; speedup vs baseline: 1.6354x; 1.3145x over previous
//
#include <hip/hip_runtime.h>
#include <math.h>

// Problem constants
#define LBATCH 4096  // tokens per mamba batch (b=2)
#define DM 768
#define RR 192
#define DI 384
#define DSTATE 16
#define DTRANK 12

typedef __attribute__((ext_vector_type(8))) short s16x8;   // 8 bf16 in 4 VGPRs
typedef __attribute__((ext_vector_type(4))) float f32x4;   // MFMA accumulator

__device__ __forceinline__ float silu_f(float x) { return x / (1.f + __expf(-x)); }
__device__ __forceinline__ float softplus_f(float x) { return x > 20.f ? x : log1pf(__expf(x)); }

__device__ __forceinline__ unsigned short f2bf(float f) {   // RNE fp32->bf16
    unsigned u = __float_as_uint(f);
    u += 0x7FFFu + ((u >> 16) & 1u);
    return (unsigned short)(u >> 16);
}

// DPP partial sums across each aligned 16-lane group (VALU pipe, no LDS).
template <int CTRL>
__device__ __forceinline__ float dpp_add(float x) {
    const int y = __builtin_amdgcn_update_dpp(0, __float_as_int(x), CTRL, 0xF, 0xF, false);
    return x + __int_as_float(y);
}

// ---------------------------------------------------------------------------
// fp32 -> bf16 cast, 4 elems/thread
// ---------------------------------------------------------------------------
__global__ __launch_bounds__(256) void cast_bf16(const float* __restrict__ in,
                                                 unsigned short* __restrict__ out, int n4)
{
    const int i = blockIdx.x * 256 + threadIdx.x;
    if (i < n4) {
        const float4 v = ((const float4*)in)[i];
        ushort4 o;
        o.x = f2bf(v.x); o.y = f2bf(v.y); o.z = f2bf(v.z); o.w = f2bf(v.w);
        ((ushort4*)out)[i] = o;
    }
}

// ---------------------------------------------------------------------------
// y_col fp32 [b][d][t]  ->  y_row bf16 [(b,t)][d]   (64x64 tiles via LDS)
// ---------------------------------------------------------------------------
__global__ __launch_bounds__(256) void transpose_cast(const float* __restrict__ ycol,
                                                      unsigned short* __restrict__ yrow)
{
    __shared__ float tile[64][65];
    const int t0 = blockIdx.x * 64, d0 = blockIdx.y * 64, b = blockIdx.z;
    const int tid = threadIdx.x;
    for (int idx = tid; idx < 1024; idx += 256) {
        const int d = idx >> 4, c4 = (idx & 15) << 2;
        const float4 v = *(const float4*)&ycol[((size_t)(b * DI + d0 + d)) * LBATCH + t0 + c4];
        tile[d][c4] = v.x; tile[d][c4 + 1] = v.y; tile[d][c4 + 2] = v.z; tile[d][c4 + 3] = v.w;
    }
    __syncthreads();
    for (int idx = tid; idx < 1024; idx += 256) {
        const int t = idx >> 4, d4 = (idx & 15) << 2;
        ushort4 o;
        o.x = f2bf(tile[d4][t]); o.y = f2bf(tile[d4 + 1][t]);
        o.z = f2bf(tile[d4 + 2][t]); o.w = f2bf(tile[d4 + 3][t]);
        *(ushort4*)&yrow[((size_t)(b * LBATCH + t0 + t)) * DI + d0 + d4] = o;
    }
}

// ---------------------------------------------------------------------------
// bf16 MFMA GEMM: C(M,N) = A(M,K) @ W(N,K)^T, 64x64 tile, 4 waves (wave: 64Mx16N)
// MODE 0: store C as bf16 row-major
// MODE 1: transposed split store -> fp32 xi_col[b][ch][t] / z_col[b][ch][t]
// MODE 2: store fp32 C = acc + X (residual), row-major
// ---------------------------------------------------------------------------
template <int MODE>
__global__ __launch_bounds__(256) void gemm_mfma(const unsigned short* __restrict__ A,
                                                 const unsigned short* __restrict__ W,
                                                 void* __restrict__ C0,
                                                 void* __restrict__ C1,
                                                 const float* __restrict__ X,
                                                 int K, int N)
{
    __shared__ unsigned short As[64 * 40];
    __shared__ unsigned short Ws[64 * 40];
    __shared__ float sC[(MODE == 1) ? 64 * 65 : 1];

    const int tid = threadIdx.x;
    const int wave = tid >> 6, lane = tid & 63;
    const int quad = lane >> 4, l16 = lane & 15;
    const int m0 = blockIdx.y * 64, n0 = blockIdx.x * 64;

    f32x4 acc[4] = {};

    const int sr = tid >> 2;          // staging row 0..63
    const int sc = (tid & 3) * 8;     // staging k-offset
    const unsigned short* Ap = A + (size_t)(m0 + sr) * K + sc;
    const unsigned short* Wp = W + (size_t)(n0 + sr) * K + sc;

    for (int k0 = 0; k0 < K; k0 += 32) {
        const s16x8 av = *(const s16x8*)(Ap + k0);
        const s16x8 wv = *(const s16x8*)(Wp + k0);
        __syncthreads();
        *(s16x8*)&As[sr * 40 + sc] = av;
        *(s16x8*)&Ws[sr * 40 + sc] = wv;
        __syncthreads();
        const s16x8 b = *(const s16x8*)&Ws[(wave * 16 + l16) * 40 + quad * 8];
#pragma unroll
        for (int mi = 0; mi < 4; ++mi) {
            const s16x8 a = *(const s16x8*)&As[(mi * 16 + l16) * 40 + quad * 8];
            acc[mi] = __builtin_amdgcn_mfma_f32_16x16x32_bf16(a, b, acc[mi], 0, 0, 0);
        }
    }

    if (MODE == 0) {
        unsigned short* Crow = (unsigned short*)C0;
#pragma unroll
        for (int mi = 0; mi < 4; ++mi)
#pragma unroll
            for (int r = 0; r < 4; ++r)
                Crow[(size_t)(m0 + mi * 16 + quad * 4 + r) * N + n0 + wave * 16 + l16] =
                    f2bf(acc[mi][r]);
    } else if (MODE == 2) {
        float* Co = (float*)C0;
#pragma unroll
        for (int mi = 0; mi < 4; ++mi)
#pragma unroll
            for (int r = 0; r < 4; ++r) {
                const size_t off =
                    (size_t)(m0 + mi * 16 + quad * 4 + r) * N + n0 + wave * 16 + l16;
                Co[off] = acc[mi][r] + X[off];
            }
    } else {
#pragma unroll
        for (int mi = 0; mi < 4; ++mi)
#pragma unroll
            for (int r = 0; r < 4; ++r)
                sC[(wave * 16 + l16) * 65 + mi * 16 + quad * 4 + r] = acc[mi][r];
        __syncthreads();
        const int b = m0 >> 12, tl0 = m0 & 4095;
        for (int idx = tid; idx < 1024; idx += 256) {
            const int nn = idx >> 4, t4 = (idx & 15) << 2;
            const float4 v = make_float4(sC[nn * 65 + t4], sC[nn * 65 + t4 + 1],
                                         sC[nn * 65 + t4 + 2], sC[nn * 65 + t4 + 3]);
            const int gch = n0 + nn;
            float* dst = (gch < DI)
                             ? (float*)C0 + ((size_t)(b * DI + gch)) * LBATCH
                             : (float*)C1 + ((size_t)(b * DI + gch - DI)) * LBATCH;
            *(float4*)(dst + tl0 + t4) = v;
        }
    }
}

// ---------------------------------------------------------------------------
// m = y @ out_proj^T (bf16 MFMA, K=384, N=192 full) + LayerNorm + exact GELU
// -> bf16 row-major G.  Tile 64M x 192N; wave = 16M x 192N (LN is wave-local).
// ---------------------------------------------------------------------------
__global__ __launch_bounds__(256) void gemm_ln_mfma(const unsigned short* __restrict__ Ab,
                                                    const unsigned short* __restrict__ Wb,
                                                    const float* __restrict__ lng,
                                                    const float* __restrict__ lnb,
                                                    unsigned short* __restrict__ G)
{
    __shared__ unsigned short As[64 * 40];
    __shared__ unsigned short Ws[192 * 40];
    const int tid = threadIdx.x;
    const int wave = tid >> 6, lane = tid & 63;
    const int quad = lane >> 4, l16 = lane & 15;
    const int m0 = blockIdx.x * 64;

    f32x4 acc[12] = {};
    const int sr = tid >> 2, sc = (tid & 3) * 8;

    for (int k0 = 0; k0 < DI; k0 += 32) {
        const s16x8 av = *(const s16x8*)(Ab + (size_t)(m0 + sr) * DI + k0 + sc);
        const s16x8 w0 = *(const s16x8*)(Wb + (size_t)sr * DI + k0 + sc);
        const s16x8 w1 = *(const s16x8*)(Wb + (size_t)(sr + 64) * DI + k0 + sc);
        const s16x8 w2 = *(const s16x8*)(Wb + (size_t)(sr + 128) * DI + k0 + sc);
        __syncthreads();
        *(s16x8*)&As[sr * 40 + sc] = av;
        *(s16x8*)&Ws[sr * 40 + sc] = w0;
        *(s16x8*)&Ws[(sr + 64) * 40 + sc] = w1;
        *(s16x8*)&Ws[(sr + 128) * 40 + sc] = w2;
        __syncthreads();
        const s16x8 a = *(const s16x8*)&As[(wave * 16 + l16) * 40 + quad * 8];
#pragma unroll
        for (int j = 0; j < 12; ++j) {
            const s16x8 b = *(const s16x8*)&Ws[(j * 16 + l16) * 40 + quad * 8];
            acc[j] = __builtin_amdgcn_mfma_f32_16x16x32_bf16(a, b, acc[j], 0, 0, 0);
        }
    }

    // LayerNorm stats per row (row = m0 + wave*16 + quad*4 + r), wave-local via DPP
    float s[4] = {0, 0, 0, 0}, q[4] = {0, 0, 0, 0};
#pragma unroll
    for (int j = 0; j < 12; ++j)
#pragma unroll
        for (int r = 0; r < 4; ++r) {
            s[r] += acc[j][r];
            q[r] = fmaf(acc[j][r], acc[j][r], q[r]);
        }
#pragma unroll
    for (int r = 0; r < 4; ++r) {
        s[r] = dpp_add<0xB1>(s[r]); s[r] = dpp_add<0x4E>(s[r]);
        s[r] = dpp_add<0x124>(s[r]); s[r] = dpp_add<0x128>(s[r]);
        q[r] = dpp_add<0xB1>(q[r]); q[r] = dpp_add<0x4E>(q[r]);
        q[r] = dpp_add<0x124>(q[r]); q[r] = dpp_add<0x128>(q[r]);
    }
    float mu[4], rs[4];
#pragma unroll
    for (int r = 0; r < 4; ++r) {
        mu[r] = s[r] * (1.f / 192.f);
        const float var = q[r] * (1.f / 192.f) - mu[r] * mu[r];
        rs[r] = rsqrtf(var + 1e-5f);
    }
    float gv[12], bv[12];
#pragma unroll
    for (int j = 0; j < 12; ++j) { gv[j] = lng[j * 16 + l16]; bv[j] = lnb[j * 16 + l16]; }
#pragma unroll
    for (int j = 0; j < 12; ++j)
#pragma unroll
        for (int r = 0; r < 4; ++r) {
            const float v = (acc[j][r] - mu[r]) * rs[r] * gv[j] + bv[j];
            const float ge = 0.5f * v * (1.f + erff(v * 0.70710678118654752f));
            G[(size_t)(m0 + wave * 16 + quad * 4 + r) * RR + j * 16 + l16] = f2bf(ge);
        }
}

// ---------------------------------------------------------------------------
// Depthwise causal conv (width 4) + SiLU.  One block per (b, channel) row.
// ---------------------------------------------------------------------------
__global__ __launch_bounds__(256) void conv_silu_kernel(const float* __restrict__ xi_col,
                                                        const float* __restrict__ cw,
                                                        const float* __restrict__ cb,
                                                        float* __restrict__ u_col)
{
    const int row = blockIdx.x;      // b*384 + c
    const int c = row % DI;
    const float* xp = xi_col + (size_t)row * LBATCH;
    float* up = u_col + (size_t)row * LBATCH;
    const float w0 = cw[c * 4 + 0], w1 = cw[c * 4 + 1], w2 = cw[c * 4 + 2], w3 = cw[c * 4 + 3];
    const float bb = cb[c];
    for (int t = threadIdx.x; t < LBATCH; t += 256) {
        const float x3 = xp[t];
        const float x2 = (t >= 1) ? xp[t - 1] : 0.f;
        const float x1 = (t >= 2) ? xp[t - 2] : 0.f;
        const float x0 = (t >= 3) ? xp[t - 3] : 0.f;
        const float v = bb + w0 * x0 + w1 * x1 + w2 * x2 + w3 * x3;
        up[t] = silu_f(v);
    }
}

// ---------------------------------------------------------------------------
// x_dbl = u @ x_proj^T (N=44, K=384), A read col-major (u_col).
// Outputs: dt row-major (8192x12), BCt interleaved [b][t][32] (B 0..15, C 16..31).
// ---------------------------------------------------------------------------
__global__ __launch_bounds__(256) void gemm_xdbl(const float* __restrict__ u_col,
                                                 const float* __restrict__ Wx,
                                                 float* __restrict__ dt,
                                                 float* __restrict__ BCt)
{
    __shared__ float As[16][68];
    __shared__ float Bs[16][68];
    __shared__ float sC[64 * 69];
    const int tid = threadIdx.x;
    const int ty = tid >> 4, tx = tid & 15;
    const int m0 = blockIdx.x * 64;
    const int b = m0 >> 12, tl0 = m0 & 4095;

    float acc[4][4];
#pragma unroll
    for (int i = 0; i < 4; ++i)
#pragma unroll
        for (int j = 0; j < 4; ++j) acc[i][j] = 0.f;

    for (int k0 = 0; k0 < DI; k0 += 16) {
        __syncthreads();
        {
            const int m = tid & 63;
            const int kk0 = tid >> 6;
#pragma unroll
            for (int r = 0; r < 4; ++r)
                As[kk0 + 4 * r][m] =
                    u_col[((size_t)(b * DI + k0 + kk0 + 4 * r)) * LBATCH + tl0 + m];
        }
        if (tid < 176) {
            const int n = tid >> 2;
            const int lk2 = (tid & 3) << 2;
            const float4 wv = *(const float4*)(Wx + (size_t)n * DI + k0 + lk2);
            Bs[lk2 + 0][n] = wv.x; Bs[lk2 + 1][n] = wv.y; Bs[lk2 + 2][n] = wv.z; Bs[lk2 + 3][n] = wv.w;
        }
        __syncthreads();
#pragma unroll
        for (int kk = 0; kk < 16; ++kk) {
            const float4 a4 = *(const float4*)&As[kk][ty << 2];
            const float4 b4 = *(const float4*)&Bs[kk][tx << 2];
            const float aa[4] = {a4.x, a4.y, a4.z, a4.w};
            const float bb[4] = {b4.x, b4.y, b4.z, b4.w};
#pragma unroll
            for (int i = 0; i < 4; ++i)
#pragma unroll
                for (int j = 0; j < 4; ++j)
                    acc[i][j] = fmaf(aa[i], bb[j], acc[i][j]);
        }
    }
    __syncthreads();
#pragma unroll
    for (int i = 0; i < 4; ++i)
#pragma unroll
        for (int j = 0; j < 4; ++j)
            sC[((ty << 2) + i) * 69 + (tx << 2) + j] = acc[i][j];
    __syncthreads();
    for (int idx = tid; idx < 64 * DTRANK; idx += 256) {
        const int t = idx / DTRANK, r = idx - t * DTRANK;
        dt[(size_t)(m0 + t) * DTRANK + r] = sC[t * 69 + r];
    }
    for (int idx = tid; idx < 64 * 32; idx += 256) {
        const int t = idx >> 5, c = idx & 31;
        BCt[((size_t)(b * LBATCH + tl0 + t)) * 32 + c] = sC[t * 69 + DTRANK + c];
    }
}

// ---------------------------------------------------------------------------
// delta = softplus(dt @ dt_proj^T + dt_proj_b), written col-major [b][d][t]
// ---------------------------------------------------------------------------
__global__ __launch_bounds__(256) void delta_kernel(const float* __restrict__ dt,
                                                    const float* __restrict__ dtw,
                                                    const float* __restrict__ dtb,
                                                    float* __restrict__ delta_col)
{
    const int t0g = blockIdx.x * 64;
    const int d0 = blockIdx.y * 64;
    const int b = t0g >> 12, tl0 = t0g & 4095;
    __shared__ float sdt[64][13];
    const int tid = threadIdx.x;
    for (int idx = tid; idx < 64 * DTRANK; idx += 256)
        sdt[idx / DTRANK][idx % DTRANK] = dt[(size_t)t0g * DTRANK + idx];
    __syncthreads();
    const int tl = tid & 63;
    const int dl0 = tid >> 6;
#pragma unroll
    for (int j = 0; j < 16; ++j) {
        const int d = d0 + dl0 + 4 * j;
        float a = dtb[d];
#pragma unroll
        for (int r = 0; r < DTRANK; ++r)
            a = fmaf(sdt[tl][r], dtw[d * DTRANK + r], a);
        delta_col[((size_t)(b * DI + d)) * LBATCH + tl0 + tl] = softplus_f(a);
    }
}

// ---------------------------------------------------------------------------
// Selective scan: two-level segmented scan, 2 barriers total (round-2 version).
// ---------------------------------------------------------------------------
__global__ __launch_bounds__(1024) void scan_kernel(const float* __restrict__ delta_col,
                                                    const float* __restrict__ u_col,
                                                    const float* __restrict__ BCt,
                                                    const float* __restrict__ z_col,
                                                    const float* __restrict__ A_log,
                                                    const float* __restrict__ Dv,
                                                    float* __restrict__ y_col)
{
    const int bd = blockIdx.x;       // b*384 + d
    const int b = bd / DI;
    const int d = bd - b * DI;
    const int tid = threadIdx.x;
    const int n = tid & 15;          // state index
    const int s = tid >> 4;          // segment index 0..63

    const float An = -__expf(A_log[d * DSTATE + n]);
    const float Dd = Dv[d];
    const float* dp = delta_col + (size_t)bd * LBATCH;
    const float* up = u_col + (size_t)bd * LBATCH;
    const float* zp = z_col + (size_t)bd * LBATCH;
    const float* bc = BCt + (size_t)b * LBATCH * 32;
    float* yp = y_col + (size_t)bd * LBATCH;

    __shared__ float aggA[64][17];
    __shared__ float aggB[64][17];
    __shared__ float hst[64][17];

    const int t0 = s * 64;

    float Ag = 1.f, Bg = 0.f;
    for (int i = 0; i < 64; i += 4) {
        const float4 d4 = *(const float4*)(dp + t0 + i);
        const float4 u4 = *(const float4*)(up + t0 + i);
        const float dls[4] = {d4.x, d4.y, d4.z, d4.w};
        const float uus[4] = {u4.x, u4.y, u4.z, u4.w};
#pragma unroll
        for (int j = 0; j < 4; ++j) {
            const int t = t0 + i + j;
            const float bm = bc[(size_t)t * 32 + n];
            const float a = __expf(dls[j] * An);
            const float bb = dls[j] * uus[j] * bm;
            Bg = fmaf(a, Bg, bb);
            Ag *= a;
        }
    }
    aggA[s][n] = Ag;
    aggB[s][n] = Bg;
    __syncthreads();

    {
        const int w = tid >> 6;
        const int lane = tid & 63;
        float sA = aggA[lane][w];
        float sB = aggB[lane][w];
#pragma unroll
        for (int o = 1; o < 64; o <<= 1) {
            const float pA = __shfl_up(sA, (unsigned)o, 64);
            const float pB = __shfl_up(sB, (unsigned)o, 64);
            if (lane >= o) { sB = fmaf(sA, pB, sB); sA *= pA; }
        }
        const float hprev = __shfl_up(sB, 1, 64);
        hst[lane][w] = (lane == 0) ? 0.f : hprev;
    }
    __syncthreads();

    float h = hst[s][n];
    for (int i = 0; i < 64; i += 4) {
        const float4 d4 = *(const float4*)(dp + t0 + i);
        const float4 u4 = *(const float4*)(up + t0 + i);
        const float4 z4 = *(const float4*)(zp + t0 + i);
        const float dls[4] = {d4.x, d4.y, d4.z, d4.w};
        const float uus[4] = {u4.x, u4.y, u4.z, u4.w};
        const float zzs[4] = {z4.x, z4.y, z4.z, z4.w};
#pragma unroll
        for (int j = 0; j < 4; ++j) {
            const int t = t0 + i + j;
            const float bm = bc[(size_t)t * 32 + n];
            const float cm = bc[(size_t)t * 32 + 16 + n];
            const float a = __expf(dls[j] * An);
            h = fmaf(a, h, dls[j] * uus[j] * bm);
            float p = h * cm;
            p = dpp_add<0xB1>(p);
            p = dpp_add<0x4E>(p);
            p = dpp_add<0x124>(p);
            p = dpp_add<0x128>(p);
            if (n == 0)
                yp[t] = (p + uus[j] * Dd) * silu_f(zzs[j]);
        }
    }
}

// ---------------------------------------------------------------------------
extern "C" void kernel_launch(void* const* d_in, const int* in_sizes, int n_in,
                              void* d_out, int out_size, void* d_ws, size_t ws_size,
                              hipStream_t stream)
{
    const float* x         = (const float*)d_in[0];
    const float* down_w    = (const float*)d_in[1];
    const float* up_w      = (const float*)d_in[2];
    const float* in_proj_w = (const float*)d_in[3];
    const float* conv_w    = (const float*)d_in[4];
    const float* conv_b    = (const float*)d_in[5];
    const float* x_proj_w  = (const float*)d_in[6];
    const float* dt_proj_w = (const float*)d_in[7];
    const float* dt_proj_b = (const float*)d_in[8];
    const float* A_log     = (const float*)d_in[9];
    const float* D_ssm     = (const float*)d_in[10];
    const float* out_proj_w= (const float*)d_in[11];
    const float* ln_g      = (const float*)d_in[12];
    const float* ln_b      = (const float*)d_in[13];
    float* out = (float*)d_out;
    float* ws = (float*)d_ws;

    // fp32 workspace
    float* xi_col    = ws;                        // 2*384*4096 = 3145728
    float* z_col     = xi_col + 3145728;          // 3145728
    float* u_col     = z_col + 3145728;           // 3145728
    float* y_col     = u_col + 3145728;           // 3145728
    float* dt        = y_col + 3145728;           // 98304
    float* BCt       = dt + 98304;                // 262144
    float* delta_col = xi_col;                    // alias: xi dead after conv
    // bf16 workspace
    unsigned short* xb     = (unsigned short*)(BCt + 262144);  // 6291456
    unsigned short* yb     = xb;                  // alias: xb dead after gemm1
    unsigned short* xdb    = xb + 6291456;        // 1572864
    unsigned short* gb     = xdb;                 // alias: xdb dead after gemm2
    unsigned short* wdownb = xdb + 1572864;       // 147456
    unsigned short* winb   = wdownb + 147456;     // 147456
    unsigned short* woutb  = winb + 147456;       // 73728
    unsigned short* wupb   = woutb + 73728;       // 147456

    // 0. casts to bf16
    cast_bf16<<<6144, 256, 0, stream>>>(x, xb, 1572864);
    cast_bf16<<<144, 256, 0, stream>>>(down_w, wdownb, 36864);
    cast_bf16<<<144, 256, 0, stream>>>(in_proj_w, winb, 36864);
    cast_bf16<<<72, 256, 0, stream>>>(out_proj_w, woutb, 18432);
    cast_bf16<<<144, 256, 0, stream>>>(up_w, wupb, 36864);
    // 1. xd = x @ down_w^T  (bf16 MFMA) -> xdb (bf16 row-major 8192x192)
    gemm_mfma<0><<<dim3(3, 128), 256, 0, stream>>>(xb, wdownb, xdb, nullptr, nullptr, DM, RR);
    // 2. xz = xd @ in_proj^T -> xi_col, z_col (fp32 col-major)
    gemm_mfma<1><<<dim3(12, 128), 256, 0, stream>>>(xdb, winb, xi_col, z_col, nullptr, RR, 2 * DI);
    // 3. depthwise conv4 + silu -> u_col
    conv_silu_kernel<<<768, 256, 0, stream>>>(xi_col, conv_w, conv_b, u_col);
    // 4. x_dbl = u @ x_proj^T -> dt, BCt
    gemm_xdbl<<<128, 256, 0, stream>>>(u_col, x_proj_w, dt, BCt);
    // 5. delta = softplus(dt @ dt_proj^T + b) -> delta_col (aliases xi_col)
    delta_kernel<<<dim3(128, 6), 256, 0, stream>>>(dt, dt_proj_w, dt_proj_b, delta_col);
    // 6. selective scan + gating -> y_col
    scan_kernel<<<768, 1024, 0, stream>>>(delta_col, u_col, BCt, z_col, A_log, D_ssm, y_col);
    // 7. y_col -> yb (bf16 row-major 8192x384)
    transpose_cast<<<dim3(64, 6, 2), 256, 0, stream>>>(y_col, yb);
    // 8. m = y @ out_proj^T + LN + GELU -> gb (bf16 row-major 8192x192)
    gemm_ln_mfma<<<128, 256, 0, stream>>>(yb, woutb, ln_g, ln_b, gb);
    // 9. out = x + g @ up_w^T (fp32 store)
    gemm_mfma<2><<<dim3(12, 128), 256, 0, stream>>>(gb, wupb, out, nullptr, x, RR, DM);
}

// Round 4
// 277.972 us; speedup vs baseline: 1.7616x; 1.0772x over previous
//
#include <hip/hip_runtime.h>
#include <math.h>

// Problem constants
#define LBATCH 4096  // tokens per mamba batch (b=2)
#define DM 768
#define RR 192
#define DI 384
#define DSTATE 16
#define DTRANK 12

typedef __attribute__((ext_vector_type(8))) short s16x8;   // 8 bf16 in 4 VGPRs
typedef __attribute__((ext_vector_type(4))) float f32x4;   // MFMA accumulator

__device__ __forceinline__ float silu_f(float x) { return x / (1.f + __expf(-x)); }
__device__ __forceinline__ float softplus_f(float x) { return x > 20.f ? x : log1pf(__expf(x)); }

__device__ __forceinline__ unsigned short f2bf(float f) {   // RNE fp32->bf16
    unsigned u = __float_as_uint(f);
    u += 0x7FFFu + ((u >> 16) & 1u);
    return (unsigned short)(u >> 16);
}

// DPP partial sums across aligned lane groups (VALU pipe, no LDS).
template <int CTRL>
__device__ __forceinline__ float dpp_add(float x) {
    const int y = __builtin_amdgcn_update_dpp(0, __float_as_int(x), CTRL, 0xF, 0xF, false);
    return x + __int_as_float(y);
}

// ---------------------------------------------------------------------------
// Cast all 4 weight matrices fp32->bf16 in one launch. blockIdx.y = tensor.
// ---------------------------------------------------------------------------
__global__ __launch_bounds__(256) void cast_w4(const float* __restrict__ w0,
                                               const float* __restrict__ w1,
                                               const float* __restrict__ w2,
                                               const float* __restrict__ w3,
                                               unsigned short* __restrict__ o0,
                                               unsigned short* __restrict__ o1,
                                               unsigned short* __restrict__ o2,
                                               unsigned short* __restrict__ o3)
{
    const int which = blockIdx.y;
    const float* src = which == 0 ? w0 : which == 1 ? w1 : which == 2 ? w2 : w3;
    unsigned short* dst = which == 0 ? o0 : which == 1 ? o1 : which == 2 ? o2 : o3;
    const int n4 = (which == 2) ? 18432 : 36864;
    const int i = blockIdx.x * 256 + threadIdx.x;
    if (i < n4) {
        const float4 v = ((const float4*)src)[i];
        ushort4 o;
        o.x = f2bf(v.x); o.y = f2bf(v.y); o.z = f2bf(v.z); o.w = f2bf(v.w);
        ((ushort4*)dst)[i] = o;
    }
}

// ---------------------------------------------------------------------------
// bf16 MFMA GEMM: C(M,N) = A(M,K) @ W(N,K)^T, 64x64 tile, 4 waves (wave: 64Mx16N)
// CVT: A is fp32, converted to bf16 during LDS staging.
// MODE 0: store C as bf16 row-major
// MODE 1: transposed split store -> fp32 xi_col[b][ch][t] / z_col[b][ch][t]
// MODE 2: store fp32 C = acc + X (residual), row-major
// ---------------------------------------------------------------------------
template <int MODE, bool CVT>
__global__ __launch_bounds__(256) void gemm_mfma(const void* __restrict__ Araw,
                                                 const unsigned short* __restrict__ W,
                                                 void* __restrict__ C0,
                                                 void* __restrict__ C1,
                                                 const float* __restrict__ X,
                                                 int K, int N)
{
    __shared__ unsigned short As[64 * 40];
    __shared__ unsigned short Ws[64 * 40];
    __shared__ float sC[(MODE == 1) ? 64 * 65 : 1];

    const int tid = threadIdx.x;
    const int wave = tid >> 6, lane = tid & 63;
    const int quad = lane >> 4, l16 = lane & 15;
    const int m0 = blockIdx.y * 64, n0 = blockIdx.x * 64;

    f32x4 acc[4] = {};

    const int sr = tid >> 2;          // staging row 0..63
    const int sc = (tid & 3) * 8;     // staging k-offset
    const unsigned short* Wp = W + (size_t)(n0 + sr) * K + sc;

    for (int k0 = 0; k0 < K; k0 += 32) {
        s16x8 av;
        if (CVT) {
            const float* Af = (const float*)Araw + (size_t)(m0 + sr) * K + sc;
            const float4 f0 = *(const float4*)(Af + k0);
            const float4 f1 = *(const float4*)(Af + k0 + 4);
            union { s16x8 v; unsigned short u[8]; } pk;
            pk.u[0] = f2bf(f0.x); pk.u[1] = f2bf(f0.y); pk.u[2] = f2bf(f0.z); pk.u[3] = f2bf(f0.w);
            pk.u[4] = f2bf(f1.x); pk.u[5] = f2bf(f1.y); pk.u[6] = f2bf(f1.z); pk.u[7] = f2bf(f1.w);
            av = pk.v;
        } else {
            const unsigned short* Ap = (const unsigned short*)Araw + (size_t)(m0 + sr) * K + sc;
            av = *(const s16x8*)(Ap + k0);
        }
        const s16x8 wv = *(const s16x8*)(Wp + k0);
        __syncthreads();
        *(s16x8*)&As[sr * 40 + sc] = av;
        *(s16x8*)&Ws[sr * 40 + sc] = wv;
        __syncthreads();
        const s16x8 b = *(const s16x8*)&Ws[(wave * 16 + l16) * 40 + quad * 8];
#pragma unroll
        for (int mi = 0; mi < 4; ++mi) {
            const s16x8 a = *(const s16x8*)&As[(mi * 16 + l16) * 40 + quad * 8];
            acc[mi] = __builtin_amdgcn_mfma_f32_16x16x32_bf16(a, b, acc[mi], 0, 0, 0);
        }
    }

    if (MODE == 0) {
        unsigned short* Crow = (unsigned short*)C0;
#pragma unroll
        for (int mi = 0; mi < 4; ++mi)
#pragma unroll
            for (int r = 0; r < 4; ++r)
                Crow[(size_t)(m0 + mi * 16 + quad * 4 + r) * N + n0 + wave * 16 + l16] =
                    f2bf(acc[mi][r]);
    } else if (MODE == 2) {
        float* Co = (float*)C0;
#pragma unroll
        for (int mi = 0; mi < 4; ++mi)
#pragma unroll
            for (int r = 0; r < 4; ++r) {
                const size_t off =
                    (size_t)(m0 + mi * 16 + quad * 4 + r) * N + n0 + wave * 16 + l16;
                Co[off] = acc[mi][r] + X[off];
            }
    } else {
#pragma unroll
        for (int mi = 0; mi < 4; ++mi)
#pragma unroll
            for (int r = 0; r < 4; ++r)
                sC[(wave * 16 + l16) * 65 + mi * 16 + quad * 4 + r] = acc[mi][r];
        __syncthreads();
        const int b = m0 >> 12, tl0 = m0 & 4095;
        for (int idx = tid; idx < 1024; idx += 256) {
            const int nn = idx >> 4, t4 = (idx & 15) << 2;
            const float4 v = make_float4(sC[nn * 65 + t4], sC[nn * 65 + t4 + 1],
                                         sC[nn * 65 + t4 + 2], sC[nn * 65 + t4 + 3]);
            const int gch = n0 + nn;
            float* dst = (gch < DI)
                             ? (float*)C0 + ((size_t)(b * DI + gch)) * LBATCH
                             : (float*)C1 + ((size_t)(b * DI + gch - DI)) * LBATCH;
            *(float4*)(dst + tl0 + t4) = v;
        }
    }
}

// ---------------------------------------------------------------------------
// m = y @ out_proj^T (bf16 MFMA, K=384, N=192) + LayerNorm + exact GELU -> bf16 G.
// A is fp32 y_col [b][d][t]: transposed + cast during LDS staging (fused).
// Tile 64M x 192N; wave = 16M x 192N (LN is wave-local via DPP).
// ---------------------------------------------------------------------------
__global__ __launch_bounds__(256) void gemm_ln_mfma(const float* __restrict__ ycol,
                                                    const unsigned short* __restrict__ Wb,
                                                    const float* __restrict__ lng,
                                                    const float* __restrict__ lnb,
                                                    unsigned short* __restrict__ G)
{
    __shared__ unsigned short As[64 * 40];
    __shared__ unsigned short Ws[192 * 40];
    const int tid = threadIdx.x;
    const int wave = tid >> 6, lane = tid & 63;
    const int quad = lane >> 4, l16 = lane & 15;
    const int m0 = blockIdx.x * 64;
    const int b = m0 >> 12, tl0 = m0 & 4095;

    f32x4 acc[12] = {};
    const int sr = tid >> 2, sc = (tid & 3) * 8;
    // A-staging map: d-pair kd2 = tid>>4 (0..15), token offset tt0 = (tid&15)*4
    const int kd2 = tid >> 4, tt0 = (tid & 15) << 2;

    for (int k0 = 0; k0 < DI; k0 += 32) {
        const float* y0 = ycol + ((size_t)(b * DI + k0 + 2 * kd2)) * LBATCH + tl0 + tt0;
        const float4 v0 = *(const float4*)y0;            // d = k0+2*kd2,   t = tt0..tt0+3
        const float4 v1 = *(const float4*)(y0 + LBATCH); // d = k0+2*kd2+1
        const s16x8 w0 = *(const s16x8*)(Wb + (size_t)sr * DI + k0 + sc);
        const s16x8 w1 = *(const s16x8*)(Wb + (size_t)(sr + 64) * DI + k0 + sc);
        const s16x8 w2 = *(const s16x8*)(Wb + (size_t)(sr + 128) * DI + k0 + sc);
        __syncthreads();
        {
            const float e0[4] = {v0.x, v0.y, v0.z, v0.w};
            const float e1[4] = {v1.x, v1.y, v1.z, v1.w};
#pragma unroll
            for (int r = 0; r < 4; ++r) {
                const unsigned pair =
                    (unsigned)f2bf(e0[r]) | ((unsigned)f2bf(e1[r]) << 16);
                *(unsigned*)&As[(tt0 + r) * 40 + 2 * kd2] = pair;
            }
        }
        *(s16x8*)&Ws[sr * 40 + sc] = w0;
        *(s16x8*)&Ws[(sr + 64) * 40 + sc] = w1;
        *(s16x8*)&Ws[(sr + 128) * 40 + sc] = w2;
        __syncthreads();
        const s16x8 a = *(const s16x8*)&As[(wave * 16 + l16) * 40 + quad * 8];
#pragma unroll
        for (int j = 0; j < 12; ++j) {
            const s16x8 bb = *(const s16x8*)&Ws[(j * 16 + l16) * 40 + quad * 8];
            acc[j] = __builtin_amdgcn_mfma_f32_16x16x32_bf16(a, bb, acc[j], 0, 0, 0);
        }
    }

    // LayerNorm stats per row (row = m0 + wave*16 + quad*4 + r), wave-local via DPP
    float s[4] = {0, 0, 0, 0}, q[4] = {0, 0, 0, 0};
#pragma unroll
    for (int j = 0; j < 12; ++j)
#pragma unroll
        for (int r = 0; r < 4; ++r) {
            s[r] += acc[j][r];
            q[r] = fmaf(acc[j][r], acc[j][r], q[r]);
        }
#pragma unroll
    for (int r = 0; r < 4; ++r) {
        s[r] = dpp_add<0xB1>(s[r]); s[r] = dpp_add<0x4E>(s[r]);
        s[r] = dpp_add<0x124>(s[r]); s[r] = dpp_add<0x128>(s[r]);
        q[r] = dpp_add<0xB1>(q[r]); q[r] = dpp_add<0x4E>(q[r]);
        q[r] = dpp_add<0x124>(q[r]); q[r] = dpp_add<0x128>(q[r]);
    }
    float mu[4], rs[4];
#pragma unroll
    for (int r = 0; r < 4; ++r) {
        mu[r] = s[r] * (1.f / 192.f);
        const float var = q[r] * (1.f / 192.f) - mu[r] * mu[r];
        rs[r] = rsqrtf(var + 1e-5f);
    }
    float gv[12], bv[12];
#pragma unroll
    for (int j = 0; j < 12; ++j) { gv[j] = lng[j * 16 + l16]; bv[j] = lnb[j * 16 + l16]; }
#pragma unroll
    for (int j = 0; j < 12; ++j)
#pragma unroll
        for (int r = 0; r < 4; ++r) {
            const float v = (acc[j][r] - mu[r]) * rs[r] * gv[j] + bv[j];
            const float ge = 0.5f * v * (1.f + erff(v * 0.70710678118654752f));
            G[(size_t)(m0 + wave * 16 + quad * 4 + r) * RR + j * 16 + l16] = f2bf(ge);
        }
}

// ---------------------------------------------------------------------------
// Depthwise causal conv (width 4) + SiLU.  One block per (b, channel) row.
// ---------------------------------------------------------------------------
__global__ __launch_bounds__(256) void conv_silu_kernel(const float* __restrict__ xi_col,
                                                        const float* __restrict__ cw,
                                                        const float* __restrict__ cb,
                                                        float* __restrict__ u_col)
{
    const int row = blockIdx.x;      // b*384 + c
    const int c = row % DI;
    const float* xp = xi_col + (size_t)row * LBATCH;
    float* up = u_col + (size_t)row * LBATCH;
    const float w0 = cw[c * 4 + 0], w1 = cw[c * 4 + 1], w2 = cw[c * 4 + 2], w3 = cw[c * 4 + 3];
    const float bb = cb[c];
    for (int t = threadIdx.x; t < LBATCH; t += 256) {
        const float x3 = xp[t];
        const float x2 = (t >= 1) ? xp[t - 1] : 0.f;
        const float x1 = (t >= 2) ? xp[t - 2] : 0.f;
        const float x0 = (t >= 3) ? xp[t - 3] : 0.f;
        const float v = bb + w0 * x0 + w1 * x1 + w2 * x2 + w3 * x3;
        up[t] = silu_f(v);
    }
}

// ---------------------------------------------------------------------------
// x_dbl = u @ x_proj^T (N=44, K=384), A read col-major (u_col).
// Outputs: dt row-major (8192x12), BCt interleaved [b][t][32] (B 0..15, C 16..31).
// ---------------------------------------------------------------------------
__global__ __launch_bounds__(256) void gemm_xdbl(const float* __restrict__ u_col,
                                                 const float* __restrict__ Wx,
                                                 float* __restrict__ dt,
                                                 float* __restrict__ BCt)
{
    __shared__ float As[16][68];
    __shared__ float Bs[16][68];
    __shared__ float sC[64 * 69];
    const int tid = threadIdx.x;
    const int ty = tid >> 4, tx = tid & 15;
    const int m0 = blockIdx.x * 64;
    const int b = m0 >> 12, tl0 = m0 & 4095;

    float acc[4][4];
#pragma unroll
    for (int i = 0; i < 4; ++i)
#pragma unroll
        for (int j = 0; j < 4; ++j) acc[i][j] = 0.f;

    for (int k0 = 0; k0 < DI; k0 += 16) {
        __syncthreads();
        {
            const int m = tid & 63;
            const int kk0 = tid >> 6;
#pragma unroll
            for (int r = 0; r < 4; ++r)
                As[kk0 + 4 * r][m] =
                    u_col[((size_t)(b * DI + k0 + kk0 + 4 * r)) * LBATCH + tl0 + m];
        }
        if (tid < 176) {
            const int n = tid >> 2;
            const int lk2 = (tid & 3) << 2;
            const float4 wv = *(const float4*)(Wx + (size_t)n * DI + k0 + lk2);
            Bs[lk2 + 0][n] = wv.x; Bs[lk2 + 1][n] = wv.y; Bs[lk2 + 2][n] = wv.z; Bs[lk2 + 3][n] = wv.w;
        }
        __syncthreads();
#pragma unroll
        for (int kk = 0; kk < 16; ++kk) {
            const float4 a4 = *(const float4*)&As[kk][ty << 2];
            const float4 b4 = *(const float4*)&Bs[kk][tx << 2];
            const float aa[4] = {a4.x, a4.y, a4.z, a4.w};
            const float bb[4] = {b4.x, b4.y, b4.z, b4.w};
#pragma unroll
            for (int i = 0; i < 4; ++i)
#pragma unroll
                for (int j = 0; j < 4; ++j)
                    acc[i][j] = fmaf(aa[i], bb[j], acc[i][j]);
        }
    }
    __syncthreads();
#pragma unroll
    for (int i = 0; i < 4; ++i)
#pragma unroll
        for (int j = 0; j < 4; ++j)
            sC[((ty << 2) + i) * 69 + (tx << 2) + j] = acc[i][j];
    __syncthreads();
    for (int idx = tid; idx < 64 * DTRANK; idx += 256) {
        const int t = idx / DTRANK, r = idx - t * DTRANK;
        dt[(size_t)(m0 + t) * DTRANK + r] = sC[t * 69 + r];
    }
    for (int idx = tid; idx < 64 * 32; idx += 256) {
        const int t = idx >> 5, c = idx & 31;
        BCt[((size_t)(b * LBATCH + tl0 + t)) * 32 + c] = sC[t * 69 + DTRANK + c];
    }
}

// ---------------------------------------------------------------------------
// delta = softplus(dt @ dt_proj^T + dt_proj_b), written col-major [b][d][t]
// ---------------------------------------------------------------------------
__global__ __launch_bounds__(256) void delta_kernel(const float* __restrict__ dt,
                                                    const float* __restrict__ dtw,
                                                    const float* __restrict__ dtb,
                                                    float* __restrict__ delta_col)
{
    const int t0g = blockIdx.x * 64;
    const int d0 = blockIdx.y * 64;
    const int b = t0g >> 12, tl0 = t0g & 4095;
    __shared__ float sdt[64][13];
    const int tid = threadIdx.x;
    for (int idx = tid; idx < 64 * DTRANK; idx += 256)
        sdt[idx / DTRANK][idx % DTRANK] = dt[(size_t)t0g * DTRANK + idx];
    __syncthreads();
    const int tl = tid & 63;
    const int dl0 = tid >> 6;
#pragma unroll
    for (int j = 0; j < 16; ++j) {
        const int d = d0 + dl0 + 4 * j;
        float a = dtb[d];
#pragma unroll
        for (int r = 0; r < DTRANK; ++r)
            a = fmaf(sdt[tl][r], dtw[d * DTRANK + r], a);
        delta_col[((size_t)(b * DI + d)) * LBATCH + tl0 + tl] = softplus_f(a);
    }
}

// ---------------------------------------------------------------------------
// Selective scan v3: 256 threads/block, 4 states per thread.
// Thread (s = tid>>2 in 0..63, n4 = tid&3): segment s (64 steps), states 4n4..4n4+3.
// Phase 1: serial affine aggregates (4 states in regs). Middle: 4 waves x 4
// sequential wave-scans over segment aggregates. Phase 2: replay with exact
// h0; 16-state sum = 3 in-thread adds + 2 quad-DPP adds; stores on n4==0.
// ---------------------------------------------------------------------------
__global__ __launch_bounds__(256) void scan_kernel(const float* __restrict__ delta_col,
                                                   const float* __restrict__ u_col,
                                                   const float* __restrict__ BCt,
                                                   const float* __restrict__ z_col,
                                                   const float* __restrict__ A_log,
                                                   const float* __restrict__ Dv,
                                                   float* __restrict__ y_col)
{
    const int bd = blockIdx.x;       // b*384 + d
    const int b = bd / DI;
    const int d = bd - b * DI;
    const int tid = threadIdx.x;
    const int n4 = tid & 3;          // state quad (states 4n4..4n4+3)
    const int s = tid >> 2;          // segment 0..63

    const float4 al = *(const float4*)(A_log + d * DSTATE + 4 * n4);
    // An2[q] = -exp(A_log) * log2(e)  -> a = exp2(delta * An2)
    float An2[4];
    An2[0] = -__expf(al.x) * 1.44269504f;
    An2[1] = -__expf(al.y) * 1.44269504f;
    An2[2] = -__expf(al.z) * 1.44269504f;
    An2[3] = -__expf(al.w) * 1.44269504f;
    const float Dd = Dv[d];

    const int t0 = s * 64;
    const float* dp = delta_col + (size_t)bd * LBATCH + t0;
    const float* up = u_col + (size_t)bd * LBATCH + t0;
    const float* zp = z_col + (size_t)bd * LBATCH + t0;
    const float* bc = BCt + ((size_t)b * LBATCH + t0) * 32 + 4 * n4;
    float* yp = y_col + (size_t)bd * LBATCH + t0;

    __shared__ float aggA[64 * 20];
    __shared__ float aggB[64 * 20];
    __shared__ float hst[64 * 20];

    // ---- phase 1: segment affine aggregate for 4 states ----
    float Ag[4] = {1.f, 1.f, 1.f, 1.f}, Bg[4] = {0.f, 0.f, 0.f, 0.f};
    {
        const float* bci = bc;
        for (int i = 0; i < 64; i += 4) {
            const float4 d4 = *(const float4*)(dp + i);
            const float4 u4 = *(const float4*)(up + i);
            const float dls[4] = {d4.x, d4.y, d4.z, d4.w};
            const float uus[4] = {u4.x, u4.y, u4.z, u4.w};
#pragma unroll
            for (int j = 0; j < 4; ++j) {
                const float4 bm4 = *(const float4*)(bci + j * 32);
                const float du = dls[j] * uus[j];
                const float bms[4] = {bm4.x, bm4.y, bm4.z, bm4.w};
#pragma unroll
                for (int q = 0; q < 4; ++q) {
                    const float a = exp2f(dls[j] * An2[q]);
                    Bg[q] = fmaf(a, Bg[q], du * bms[q]);
                    Ag[q] *= a;
                }
            }
            bci += 128;
        }
    }
    *(float4*)&aggA[s * 20 + 4 * n4] = make_float4(Ag[0], Ag[1], Ag[2], Ag[3]);
    *(float4*)&aggB[s * 20 + 4 * n4] = make_float4(Bg[0], Bg[1], Bg[2], Bg[3]);
    __syncthreads();

    // ---- middle: per-state inclusive scan over 64 segment aggregates ----
    {
        const int w = tid >> 6;      // wave 0..3 -> states 4w..4w+3
        const int lane = tid & 63;   // segment
#pragma unroll
        for (int r = 0; r < 4; ++r) {
            const int n = w * 4 + r;
            float sA = aggA[lane * 20 + n];
            float sB = aggB[lane * 20 + n];
#pragma unroll
            for (int o = 1; o < 64; o <<= 1) {
                const float pA = __shfl_up(sA, (unsigned)o, 64);
                const float pB = __shfl_up(sB, (unsigned)o, 64);
                if (lane >= o) { sB = fmaf(sA, pB, sB); sA *= pA; }
            }
            const float hprev = __shfl_up(sB, 1, 64);
            hst[lane * 20 + n] = (lane == 0) ? 0.f : hprev;
        }
    }
    __syncthreads();

    // ---- phase 2: replay with exact incoming state ----
    const float4 h4 = *(const float4*)&hst[s * 20 + 4 * n4];
    float h[4] = {h4.x, h4.y, h4.z, h4.w};
    {
        const float* bci = bc;
        for (int i = 0; i < 64; i += 4) {
            const float4 d4 = *(const float4*)(dp + i);
            const float4 u4 = *(const float4*)(up + i);
            const float4 z4 = *(const float4*)(zp + i);
            const float dls[4] = {d4.x, d4.y, d4.z, d4.w};
            const float uus[4] = {u4.x, u4.y, u4.z, u4.w};
            const float zzs[4] = {z4.x, z4.y, z4.z, z4.w};
#pragma unroll
            for (int j = 0; j < 4; ++j) {
                const float4 bm4 = *(const float4*)(bci + j * 32);
                const float4 cm4 = *(const float4*)(bci + j * 32 + 16);
                const float du = dls[j] * uus[j];
                const float bms[4] = {bm4.x, bm4.y, bm4.z, bm4.w};
                const float cms[4] = {cm4.x, cm4.y, cm4.z, cm4.w};
                float p = 0.f;
#pragma unroll
                for (int q = 0; q < 4; ++q) {
                    const float a = exp2f(dls[j] * An2[q]);
                    h[q] = fmaf(a, h[q], du * bms[q]);
                    p = fmaf(h[q], cms[q], p);
                }
                p = dpp_add<0xB1>(p);   // quad xor1
                p = dpp_add<0x4E>(p);   // quad xor2
                if (n4 == 0)
                    yp[i + j] = (p + uus[j] * Dd) * silu_f(zzs[j]);
            }
            bci += 128;
        }
    }
}

// ---------------------------------------------------------------------------
extern "C" void kernel_launch(void* const* d_in, const int* in_sizes, int n_in,
                              void* d_out, int out_size, void* d_ws, size_t ws_size,
                              hipStream_t stream)
{
    const float* x         = (const float*)d_in[0];
    const float* down_w    = (const float*)d_in[1];
    const float* up_w      = (const float*)d_in[2];
    const float* in_proj_w = (const float*)d_in[3];
    const float* conv_w    = (const float*)d_in[4];
    const float* conv_b    = (const float*)d_in[5];
    const float* x_proj_w  = (const float*)d_in[6];
    const float* dt_proj_w = (const float*)d_in[7];
    const float* dt_proj_b = (const float*)d_in[8];
    const float* A_log     = (const float*)d_in[9];
    const float* D_ssm     = (const float*)d_in[10];
    const float* out_proj_w= (const float*)d_in[11];
    const float* ln_g      = (const float*)d_in[12];
    const float* ln_b      = (const float*)d_in[13];
    float* out = (float*)d_out;
    float* ws = (float*)d_ws;

    // fp32 workspace
    float* xi_col    = ws;                        // 2*384*4096 = 3145728
    float* z_col     = xi_col + 3145728;          // 3145728
    float* u_col     = z_col + 3145728;           // 3145728
    float* y_col     = u_col + 3145728;           // 3145728
    float* dt        = y_col + 3145728;           // 98304
    float* BCt       = dt + 98304;                // 262144
    float* delta_col = xi_col;                    // alias: xi dead after conv
    // bf16 workspace
    unsigned short* xdb    = (unsigned short*)(BCt + 262144);  // 1572864
    unsigned short* gb     = xdb;                 // alias: xdb dead after gemm2
    unsigned short* wdownb = xdb + 1572864;       // 147456
    unsigned short* winb   = wdownb + 147456;     // 147456
    unsigned short* woutb  = winb + 147456;       // 73728
    unsigned short* wupb   = woutb + 73728;       // 147456

    // 0. all weight casts in one launch
    cast_w4<<<dim3(144, 4), 256, 0, stream>>>(down_w, in_proj_w, out_proj_w, up_w,
                                              wdownb, winb, woutb, wupb);
    // 1. xd = x @ down_w^T  (fp32 A converted in staging) -> xdb bf16 row-major
    gemm_mfma<0, true><<<dim3(3, 128), 256, 0, stream>>>(x, wdownb, xdb, nullptr, nullptr, DM, RR);
    // 2. xz = xd @ in_proj^T -> xi_col, z_col (fp32 col-major)
    gemm_mfma<1, false><<<dim3(12, 128), 256, 0, stream>>>(xdb, winb, xi_col, z_col, nullptr, RR, 2 * DI);
    // 3. depthwise conv4 + silu -> u_col
    conv_silu_kernel<<<768, 256, 0, stream>>>(xi_col, conv_w, conv_b, u_col);
    // 4. x_dbl = u @ x_proj^T -> dt, BCt
    gemm_xdbl<<<128, 256, 0, stream>>>(u_col, x_proj_w, dt, BCt);
    // 5. delta = softplus(dt @ dt_proj^T + b) -> delta_col (aliases xi_col)
    delta_kernel<<<dim3(128, 6), 256, 0, stream>>>(dt, dt_proj_w, dt_proj_b, delta_col);
    // 6. selective scan v3 + gating -> y_col
    scan_kernel<<<768, 256, 0, stream>>>(delta_col, u_col, BCt, z_col, A_log, D_ssm, y_col);
    // 7. m = y @ out_proj^T + LN + GELU (transpose fused in staging) -> gb
    gemm_ln_mfma<<<128, 256, 0, stream>>>(y_col, woutb, ln_g, ln_b, gb);
    // 8. out = x + g @ up_w^T (fp32 store)
    gemm_mfma<2, false><<<dim3(12, 128), 256, 0, stream>>>(gb, wupb, out, nullptr, x, RR, DM);
}